// Round 6
// baseline (110.509 us; speedup 1.0000x reference)
//
#include <hip/hip_runtime.h>

// Problem constants (match reference)
#define BATCH 4096
#define VOCAB 30000
#define SETSZ 64
#define LAMBDA_REG 10.0f

typedef float f4 __attribute__((ext_vector_type(4)));

// ---------------------------------------------------------------------------
// Single fused kernel: one block (256 threads) per row.
//   Phase 0: stage targets, ISSUE the 64 gather loads early (latency hides
//            under the streaming phase).
//   Phase 1 (all 4 waves): stream the row with 8 back-to-back nontemporal
//            float4 loads per iter (proven best flavor, round 5):
//            sumsq = sum p^2, expsum = sum exp(p).
//   Phase 2 (wave 0): dedupe targets (scatter idempotent), combine, and
//            atomicAdd the per-row loss into out[0] (device-scope atomic =
//            XCD-safe; 4096 adds to one address is negligible contention).
//            NO fence, NO last-block pattern (round-3 regression banned).
// out[0] is zeroed by a 4-byte hipMemsetAsync each call (graph-safe).
// ---------------------------------------------------------------------------
__global__ __launch_bounds__(256) void fused_loss_kernel(
    const float* __restrict__ pred,
    const int* __restrict__ target,
    const float* __restrict__ weights,
    float* __restrict__ out) {
  const int row = blockIdx.x;
  const size_t base = (size_t)row * VOCAB;
  const f4* p = reinterpret_cast<const f4*>(pred + base);

  __shared__ float s_ss[4], s_es[4];
  __shared__ int tg[SETSZ];

  // ---- Phase 0: stage targets + issue gather early ----
  int my = 0;
  float pv = 0.f;
  if (threadIdx.x < SETSZ) {
    my = target[row * SETSZ + threadIdx.x];
    tg[threadIdx.x] = my;
    pv = pred[base + my];   // in flight during phase 1; waitcnt lands at use
  }

  // ---- Phase 1: streaming reduction, 8 nt loads in flight per iter ----
  constexpr int N4 = VOCAB / 4;  // 7500 f4 per row
  float ss = 0.f, es = 0.f;
  int j = threadIdx.x;
  for (; j + 1792 < N4; j += 2048) {
    f4 v0 = __builtin_nontemporal_load(p + j);
    f4 v1 = __builtin_nontemporal_load(p + j + 256);
    f4 v2 = __builtin_nontemporal_load(p + j + 512);
    f4 v3 = __builtin_nontemporal_load(p + j + 768);
    f4 v4 = __builtin_nontemporal_load(p + j + 1024);
    f4 v5 = __builtin_nontemporal_load(p + j + 1280);
    f4 v6 = __builtin_nontemporal_load(p + j + 1536);
    f4 v7 = __builtin_nontemporal_load(p + j + 1792);
    ss += v0[0]*v0[0] + v0[1]*v0[1] + v0[2]*v0[2] + v0[3]*v0[3];
    es += __expf(v0[0]) + __expf(v0[1]) + __expf(v0[2]) + __expf(v0[3]);
    ss += v1[0]*v1[0] + v1[1]*v1[1] + v1[2]*v1[2] + v1[3]*v1[3];
    es += __expf(v1[0]) + __expf(v1[1]) + __expf(v1[2]) + __expf(v1[3]);
    ss += v2[0]*v2[0] + v2[1]*v2[1] + v2[2]*v2[2] + v2[3]*v2[3];
    es += __expf(v2[0]) + __expf(v2[1]) + __expf(v2[2]) + __expf(v2[3]);
    ss += v3[0]*v3[0] + v3[1]*v3[1] + v3[2]*v3[2] + v3[3]*v3[3];
    es += __expf(v3[0]) + __expf(v3[1]) + __expf(v3[2]) + __expf(v3[3]);
    ss += v4[0]*v4[0] + v4[1]*v4[1] + v4[2]*v4[2] + v4[3]*v4[3];
    es += __expf(v4[0]) + __expf(v4[1]) + __expf(v4[2]) + __expf(v4[3]);
    ss += v5[0]*v5[0] + v5[1]*v5[1] + v5[2]*v5[2] + v5[3]*v5[3];
    es += __expf(v5[0]) + __expf(v5[1]) + __expf(v5[2]) + __expf(v5[3]);
    ss += v6[0]*v6[0] + v6[1]*v6[1] + v6[2]*v6[2] + v6[3]*v6[3];
    es += __expf(v6[0]) + __expf(v6[1]) + __expf(v6[2]) + __expf(v6[3]);
    ss += v7[0]*v7[0] + v7[1]*v7[1] + v7[2]*v7[2] + v7[3]*v7[3];
    es += __expf(v7[0]) + __expf(v7[1]) + __expf(v7[2]) + __expf(v7[3]);
  }
  for (; j < N4; j += 256) {
    f4 a = __builtin_nontemporal_load(p + j);
    ss += a[0]*a[0] + a[1]*a[1] + a[2]*a[2] + a[3]*a[3];
    es += __expf(a[0]) + __expf(a[1]) + __expf(a[2]) + __expf(a[3]);
  }

  #pragma unroll
  for (int off = 32; off > 0; off >>= 1) {
    ss += __shfl_down(ss, off, 64);
    es += __shfl_down(es, off, 64);
  }
  const int wave = threadIdx.x >> 6;
  const int lane = threadIdx.x & 63;
  if (lane == 0) { s_ss[wave] = ss; s_es[wave] = es; }
  __syncthreads();

  // ---- Phase 2: target handling on wave 0, atomic accumulate ----
  if (threadIdx.x < SETSZ) {
    bool keep = true;
    for (int k = 0; k < threadIdx.x; ++k) {
      if (tg[k] == my) { keep = false; break; }
    }

    float c_mse = 0.f, c_pos = 0.f, c_exp = 0.f, cnt = 0.f;
    if (keep) {
      c_mse = 1.f - 2.f * pv;   // (p-1)^2 - p^2
      c_pos = __expf(-pv);
      c_exp = __expf(pv);
      cnt = 1.f;
    }

    #pragma unroll
    for (int off = 32; off > 0; off >>= 1) {
      c_mse += __shfl_down(c_mse, off, 64);
      c_pos += __shfl_down(c_pos, off, 64);
      c_exp += __shfl_down(c_exp, off, 64);
      cnt   += __shfl_down(cnt,   off, 64);
    }

    if (threadIdx.x == 0) {
      const float sumsq  = s_ss[0] + s_ss[1] + s_ss[2] + s_ss[3];
      const float expsum = s_es[0] + s_es[1] + s_es[2] + s_es[3];
      const float n_pos = cnt;
      const float n_neg = (float)VOCAB - n_pos;
      const float mse   = weights[row] * (sumsq + c_mse);
      const float setl  = c_pos * (expsum - c_exp) / (n_pos * n_neg);
      const float rl    = (mse + LAMBDA_REG * setl) * (1.0f / (float)BATCH);
      atomicAdd(out, rl);  // device-scope, XCD-safe
    }
  }
}

extern "C" void kernel_launch(void* const* d_in, const int* in_sizes, int n_in,
                              void* d_out, int out_size, void* d_ws, size_t ws_size,
                              hipStream_t stream) {
  const float* pred    = (const float*)d_in[0];
  const int*   target  = (const int*)d_in[1];
  const float* weights = (const float*)d_in[2];
  float* out = (float*)d_out;

  // zero the accumulator each call (graph-capture-safe, 4 bytes)
  hipMemsetAsync(out, 0, sizeof(float), stream);

  fused_loss_kernel<<<BATCH, 256, 0, stream>>>(pred, target, weights, out);
}

// Round 7
// 91.654 us; speedup vs baseline: 1.2057x; 1.2057x over previous
//
#include <hip/hip_runtime.h>

// Problem constants (match reference)
#define BATCH 4096
#define VOCAB 30000
#define SETSZ 64
#define LAMBDA_REG 10.0f

typedef float f4 __attribute__((ext_vector_type(4)));

#define ACC4(v)  do { ss += v[0]*v[0] + v[1]*v[1] + v[2]*v[2] + v[3]*v[3]; \
                      es += __expf(v[0]) + __expf(v[1]) + __expf(v[2]) + __expf(v[3]); } while (0)

// ---------------------------------------------------------------------------
// Fused kernel: one block (256 threads) per row. Round-5 proven skeleton
// (best: 91.9 us). Banned regressions: last-block fence (r3, 3x), 4-byte
// memset + atomicAdd-to-out (r6, +18us).
// This round: deep-batch the WHOLE stream. Each thread owns elements
// k=0..29 at j = tid + 256k (threads 0..75 own k=29). Batches of
// 8/8/8/5 back-to-back nontemporal loads + 1 predicated clamped load
// -- no 1-deep tail iterations (was 20% of the stream at 1-deep MLP).
// ---------------------------------------------------------------------------
__global__ __launch_bounds__(256) void fused_row_kernel(
    const float* __restrict__ pred,
    const int* __restrict__ target,
    const float* __restrict__ weights,
    float* __restrict__ row_loss) {
  const int row = blockIdx.x;
  const size_t base = (size_t)row * VOCAB;
  const f4* p = reinterpret_cast<const f4*>(pred + base);
  const int tid = threadIdx.x;

  __shared__ float s_ss[4], s_es[4];
  __shared__ int tg[SETSZ];

  // stage targets (wave 0); gather happens in phase 2 (round-5 placement)
  int my = 0;
  if (tid < SETSZ) {
    my = target[row * SETSZ + tid];
    tg[tid] = my;
  }

  // ---- Phase 1: streaming reduction, all loads in deep batches ----
  constexpr int N4 = VOCAB / 4;        // 7500 f4 per row
  constexpr int REM = N4 - 29 * 256;   // 76: threads 0..75 own element k=29
  float ss = 0.f, es = 0.f;

  {
    // k = 0..7, 8..15, 16..23 : three 8-deep batches (all threads full)
    #pragma unroll
    for (int b = 0; b < 3; ++b) {
      const int j = tid + b * 2048;
      f4 v0 = __builtin_nontemporal_load(p + j);
      f4 v1 = __builtin_nontemporal_load(p + j + 256);
      f4 v2 = __builtin_nontemporal_load(p + j + 512);
      f4 v3 = __builtin_nontemporal_load(p + j + 768);
      f4 v4 = __builtin_nontemporal_load(p + j + 1024);
      f4 v5 = __builtin_nontemporal_load(p + j + 1280);
      f4 v6 = __builtin_nontemporal_load(p + j + 1536);
      f4 v7 = __builtin_nontemporal_load(p + j + 1792);
      ACC4(v0); ACC4(v1); ACC4(v2); ACC4(v3);
      ACC4(v4); ACC4(v5); ACC4(v6); ACC4(v7);
    }
    // k = 24..28 : 5-deep batch (all threads full) + k=29 predicated
    const int j = tid + 3 * 2048;               // 6144 + tid
    const int jlast = (tid < REM) ? (tid + 29 * 256) : (N4 - 1);  // clamped
    f4 v0 = __builtin_nontemporal_load(p + j);
    f4 v1 = __builtin_nontemporal_load(p + j + 256);
    f4 v2 = __builtin_nontemporal_load(p + j + 512);
    f4 v3 = __builtin_nontemporal_load(p + j + 768);
    f4 v4 = __builtin_nontemporal_load(p + j + 1024);
    f4 v5 = __builtin_nontemporal_load(p + jlast);
    ACC4(v0); ACC4(v1); ACC4(v2); ACC4(v3); ACC4(v4);
    if (tid < REM) { ACC4(v5); }
  }

  #pragma unroll
  for (int off = 32; off > 0; off >>= 1) {
    ss += __shfl_down(ss, off, 64);
    es += __shfl_down(es, off, 64);
  }
  const int wave = tid >> 6;
  const int lane = tid & 63;
  if (lane == 0) { s_ss[wave] = ss; s_es[wave] = es; }
  __syncthreads();

  // ---- Phase 2: target handling on wave 0 ----
  if (tid < SETSZ) {
    bool keep = true;
    for (int k = 0; k < tid; ++k) {
      if (tg[k] == my) { keep = false; break; }
    }

    float c_mse = 0.f, c_pos = 0.f, c_exp = 0.f, cnt = 0.f;
    if (keep) {
      const float pv = pred[base + my];
      c_mse = 1.f - 2.f * pv;   // (p-1)^2 - p^2
      c_pos = __expf(-pv);
      c_exp = __expf(pv);
      cnt = 1.f;
    }

    #pragma unroll
    for (int off = 32; off > 0; off >>= 1) {
      c_mse += __shfl_down(c_mse, off, 64);
      c_pos += __shfl_down(c_pos, off, 64);
      c_exp += __shfl_down(c_exp, off, 64);
      cnt   += __shfl_down(cnt,   off, 64);
    }

    if (tid == 0) {
      const float sumsq  = s_ss[0] + s_ss[1] + s_ss[2] + s_ss[3];
      const float expsum = s_es[0] + s_es[1] + s_es[2] + s_es[3];
      const float n_pos = cnt;
      const float n_neg = (float)VOCAB - n_pos;
      const float mse   = weights[row] * (sumsq + c_mse);
      const float setl  = c_pos * (expsum - c_exp) / (n_pos * n_neg);
      row_loss[row] = (mse + LAMBDA_REG * setl) * (1.0f / (float)BATCH);
    }
  }
}

// ---------------------------------------------------------------------------
// Final deterministic reduction of 4096 row losses -> d_out[0].
// Single block, fixed tree order -> bit-identical across replays.
// ---------------------------------------------------------------------------
__global__ __launch_bounds__(256) void final_reduce_kernel(
    const float* __restrict__ row_loss,
    float* __restrict__ out) {
  float s = 0.f;
  for (int j = threadIdx.x; j < BATCH; j += 256) s += row_loss[j];

  #pragma unroll
  for (int off = 32; off > 0; off >>= 1) s += __shfl_down(s, off, 64);

  __shared__ float sm[4];
  const int wave = threadIdx.x >> 6;
  const int lane = threadIdx.x & 63;
  if (lane == 0) sm[wave] = s;
  __syncthreads();
  if (threadIdx.x == 0) out[0] = sm[0] + sm[1] + sm[2] + sm[3];
}

extern "C" void kernel_launch(void* const* d_in, const int* in_sizes, int n_in,
                              void* d_out, int out_size, void* d_ws, size_t ws_size,
                              hipStream_t stream) {
  const float* pred    = (const float*)d_in[0];
  const int*   target  = (const int*)d_in[1];
  const float* weights = (const float*)d_in[2];
  float* out = (float*)d_out;

  float* row_loss = (float*)d_ws;  // BATCH floats

  fused_row_kernel<<<BATCH, 256, 0, stream>>>(pred, target, weights, row_loss);
  final_reduce_kernel<<<1, 256, 0, stream>>>(row_loss, out);
}